// Round 9
// baseline (489.613 us; speedup 1.0000x reference)
//
#include <hip/hip_runtime.h>
#include <hip/hip_bf16.h>
#include <hip/hip_cooperative_groups.h>

namespace cg = cooperative_groups;

#define FEAT 128
#define NRELS 8
#define KTOT 1024          // NRELS * FEAT
#define BN 32              // dst nodes per tile
#define ECAP 256           // slab capacity per 32-node bucket (avg ~192)
#define CPAD 16            // cursor padding: one int per 64B line

typedef __bf16 bf16_t;
typedef __bf16 bf16x2_t __attribute__((ext_vector_type(2)));
typedef __bf16 bf16x8_t __attribute__((ext_vector_type(8)));
typedef float f32x4 __attribute__((ext_vector_type(4)));

struct __align__(8) PackedEdge { int row; float scale; };
// row = (src<<8) | (local<<3) | rel ; key = row & 255 ; src = row >> 8

static inline size_t align256(size_t x) { return (x + 255) & ~(size_t)255; }

// ---------------------------------------------------------------------------
// Per-node prep: h row -> hb bf16, plus 8-rel sigmoid gate (verified r4-r8).
__device__ __forceinline__ void do_prep(int node, int lane,
                                        const float* __restrict__ h,
                                        const float* __restrict__ gwt,
                                        float* __restrict__ sg,
                                        bf16_t* __restrict__ hb) {
    float2 hv2 = *reinterpret_cast<const float2*>(h + (size_t)node * FEAT + lane * 2);
    bf16x2_t hc;
    hc.x = (bf16_t)hv2.x;
    hc.y = (bf16_t)hv2.y;
    *reinterpret_cast<bf16x2_t*>(hb + (size_t)node * FEAT + lane * 2) = hc;

    int r = lane >> 3;          // relation 0..7
    int g = lane & 7;           // d-group
    const float4* hp = reinterpret_cast<const float4*>(h + (size_t)node * FEAT + g * 16);
    const float4* wp = reinterpret_cast<const float4*>(gwt + r * FEAT + g * 16);
    float s = 0.f;
#pragma unroll
    for (int i = 0; i < 4; ++i) {
        float4 a = hp[i];
        float4 b = wp[i];
        s += a.x * b.x + a.y * b.y + a.z * b.z + a.w * b.w;
    }
    s += __shfl_xor(s, 1, 64);
    s += __shfl_xor(s, 2, 64);
    s += __shfl_xor(s, 4, 64);
    if (g == 0) sg[(size_t)node * NRELS + r] = 1.0f / (1.0f + __expf(-s));
}

// ---------------------------------------------------------------------------
// Per-edge fill into fixed-capacity per-bucket slabs (verified r8).
__device__ __forceinline__ void do_fill(int e, const int* __restrict__ src,
                                        const int* __restrict__ dstv,
                                        const int* __restrict__ rel,
                                        const float* __restrict__ nrm,
                                        const float* __restrict__ sg,
                                        int* __restrict__ cur,
                                        PackedEdge* __restrict__ slab,
                                        PackedEdge* __restrict__ ovfrec,
                                        int* __restrict__ ovfbk,
                                        int* __restrict__ ovfcnt) {
    int d = dstv[e];
    int s = src[e];
    int r = rel[e];
    int bk = d >> 5;
    PackedEdge p;
    p.row = (s << 8) | ((d & 31) << 3) | r;
    p.scale = nrm[e] * sg[(size_t)s * NRELS + r];
    int pos = atomicAdd(&cur[bk * CPAD], 1);
    if (pos < ECAP) {
        slab[(size_t)bk * ECAP + pos] = p;
    } else {
        int op = atomicAdd(ovfcnt, 1);
        ovfrec[op] = p;
        ovfbk[op] = bk;
    }
}

// ---------------------------------------------------------------------------
// One 32-node tile: LDS counting sort + aggregate + GEMM + relu store.
// VERBATIM round-8 k_aggemm body (harness-verified), with tile index and the
// 4-deep bv ring passed in. The PB loop leaves bv0..bv3 holding ks=0..3 again
// (self-restoring ring), so the ring persists across tiles.
__device__ __forceinline__ void tile_body(
    int tile, int t, const bf16_t* __restrict__ hb, const bf16_t* __restrict__ wt2,
    const PackedEdge* __restrict__ slab, const int* __restrict__ cur,
    const PackedEdge* __restrict__ ovfrec, const int* __restrict__ ovfbk, int novf,
    float* __restrict__ out, int nnodes,
    char* lds_raw, PackedEdge* elist, int* kcnt, int* kbase, int* kwork,
    const bf16_t* bp, bf16x8_t& bv0, bf16x8_t& bv1, bf16x8_t& bv2, bf16x8_t& bv3) {
    float* cst = (float*)lds_raw;                 // aliased C-stage [32][132]
    const int nb0 = tile * BN;
    const int lane = t & 63;
    const int wv = t >> 6;               // 0..7
    const int l15 = lane & 15;
    const int lhi = lane >> 4;

    // zero agg tile
    {
        f32x4 z = {0.f, 0.f, 0.f, 0.f};
#pragma unroll
        for (int i = 0; i < 8; ++i)
            reinterpret_cast<f32x4*>(lds_raw)[t + i * 512] = z;
    }

    const int cnt = cur[tile * CPAD];
    const int nE = cnt < ECAP ? cnt : ECAP;
    if (t < 256) kcnt[t] = 0;
    __syncthreads();

    // coalesced slab load + count
    PackedEdge myrec = {0, 0.f};
    if (t < nE) {
        myrec = slab[(size_t)tile * ECAP + t];
        atomicAdd(&kcnt[myrec.row & 255], 1);
    }
    __syncthreads();

    // 64-lane shfl scan over 256 counters (wave 0)
    if (t < 64) {
        int c0 = kcnt[t * 4], c1 = kcnt[t * 4 + 1];
        int c2 = kcnt[t * 4 + 2], c3 = kcnt[t * 4 + 3];
        int tot = c0 + c1 + c2 + c3;
        int incl = tot;
#pragma unroll
        for (int off = 1; off < 64; off <<= 1) {
            int y = __shfl_up(incl, off, 64);
            if (t >= off) incl += y;
        }
        int excl = incl - tot;
        kbase[t * 4] = excl;               kwork[t * 4] = excl;
        kbase[t * 4 + 1] = excl + c0;      kwork[t * 4 + 1] = excl + c0;
        kbase[t * 4 + 2] = excl + c0 + c1; kwork[t * 4 + 2] = excl + c0 + c1;
        kbase[t * 4 + 3] = excl + c0 + c1 + c2;
        kwork[t * 4 + 3] = excl + c0 + c1 + c2;
        if (t == 63) kbase[256] = excl + tot;   // = nE
    }
    __syncthreads();

    // scatter into sorted elist
    if (t < nE) elist[atomicAdd(&kwork[myrec.row & 255], 1)] = myrec;
    __syncthreads();

    // ---------------- Phase A: per-node aggregation ----------------
    {
        const int g = t >> 4;            // group = local node 0..31
        const int il = t & 15;
        const int sw = g & 15;
        const int jbeg = kbase[g * 8];
        const int jend = kbase[g * 8 + 8];
        if (jbeg < jend) {
            float a[8];
#pragma unroll
            for (int i = 0; i < 8; ++i) a[i] = 0.f;
            int cur_r;

            auto ldrec = [&](int idx) {
                return elist[idx < jend ? idx : jend - 1];   // LDS broadcast
            };
            auto ldrow = [&](const PackedEdge& p) {
                return *reinterpret_cast<const bf16x8_t*>(
                    hb + ((size_t)(p.row >> 8) << 7) + il * 8);
            };
            auto flush = [&](int rr) {       // RMW add (zeros on first touch)
                int chunk = (rr * 16 + il) ^ sw;
                bf16_t* dp = reinterpret_cast<bf16_t*>(
                    lds_raw + (size_t)g * 2048 + chunk * 16);
                bf16x8_t old = *reinterpret_cast<const bf16x8_t*>(dp);
                bf16x8_t o;
#pragma unroll
                for (int i = 0; i < 8; ++i) o[i] = (bf16_t)((float)old[i] + a[i]);
                *reinterpret_cast<bf16x8_t*>(dp) = o;
            };
            auto consume = [&](const PackedEdge& p, const bf16x8_t& v, int idx) {
                if (idx < jend) {
                    int r = p.row & 7;
                    if (r != cur_r) {        // group-uniform branch
                        flush(cur_r);
#pragma unroll
                        for (int i = 0; i < 8; ++i) a[i] = 0.f;
                        cur_r = r;
                    }
                    float s = p.scale;
#pragma unroll
                    for (int i = 0; i < 8; ++i) a[i] += (float)v[i] * s;
                }
            };

            PackedEdge p0 = ldrec(jbeg), p1 = ldrec(jbeg + 1);
            PackedEdge p2 = ldrec(jbeg + 2), p3 = ldrec(jbeg + 3);
            PackedEdge q0 = ldrec(jbeg + 4), q1 = ldrec(jbeg + 5);
            PackedEdge q2 = ldrec(jbeg + 6), q3 = ldrec(jbeg + 7);
            bf16x8_t v0 = ldrow(p0);
            bf16x8_t v1 = ldrow(p1);
            bf16x8_t v2 = ldrow(p2);
            bf16x8_t v3 = ldrow(p3);
            cur_r = p0.row & 7;

#pragma unroll 1
            for (int j = jbeg; j < jend; j += 4) {
                PackedEdge r0 = ldrec(j + 8), r1 = ldrec(j + 9);
                PackedEdge r2 = ldrec(j + 10), r3 = ldrec(j + 11);
                consume(p0, v0, j);
                consume(p1, v1, j + 1);
                consume(p2, v2, j + 2);
                consume(p3, v3, j + 3);
                v0 = ldrow(q0); v1 = ldrow(q1); v2 = ldrow(q2); v3 = ldrow(q3);
                p0 = q0; p1 = q1; p2 = q2; p3 = q3;
                q0 = r0; q1 = r1; q2 = r2; q3 = r3;
            }
            flush(cur_r);
        }

        // -------- rare overflow drain (normally novf == 0) --------
        if (novf > 0) {
#pragma unroll 1
            for (int i = 0; i < novf; ++i) {
                if (ovfbk[i] != tile) continue;
                PackedEdge p = ovfrec[i];
                if (((p.row >> 3) & 31) != g) continue;
                bf16x8_t v = *reinterpret_cast<const bf16x8_t*>(
                    hb + ((size_t)(p.row >> 8) << 7) + il * 8);
                int chunk = ((p.row & 7) * 16 + il) ^ sw;
                bf16_t* dp = reinterpret_cast<bf16_t*>(
                    lds_raw + (size_t)g * 2048 + chunk * 16);
                bf16x8_t old = *reinterpret_cast<const bf16x8_t*>(dp);
                bf16x8_t o;
#pragma unroll
                for (int k = 0; k < 8; ++k)
                    o[k] = (bf16_t)((float)old[k] + (float)v[k] * p.scale);
                *reinterpret_cast<bf16x8_t*>(dp) = o;
            }
        }
    }
    __syncthreads();

    // ---------------- Phase B: GEMM with 4-deep bv prefetch ----------------
    f32x4 acc0 = {0.f, 0.f, 0.f, 0.f};
    f32x4 acc1 = {0.f, 0.f, 0.f, 0.f};
    const char* a0p = lds_raw + (size_t)l15 * 2048;        // node rows 0..15
    const char* a1p = a0p + 16 * 2048;                     // node rows 16..31
    const int swb = l15;                 // (16+l15)&15 == l15 : matches write

#define PB_STEP(I, BV)                                                         \
    {                                                                          \
        int ks = ks0 + (I);                                                    \
        int coff = ((ks * 4 + lhi) ^ swb) << 4;                                \
        bf16x8_t av0 = *reinterpret_cast<const bf16x8_t*>(a0p + coff);         \
        bf16x8_t av1 = *reinterpret_cast<const bf16x8_t*>(a1p + coff);         \
        bf16x8_t nxt = *reinterpret_cast<const bf16x8_t*>(                     \
            bp + (((ks + 4) & 31) * 32));                                      \
        acc0 = __builtin_amdgcn_mfma_f32_16x16x32_bf16(av0, BV, acc0, 0, 0, 0);\
        acc1 = __builtin_amdgcn_mfma_f32_16x16x32_bf16(av1, BV, acc1, 0, 0, 0);\
        BV = nxt;                                                              \
    }

#pragma unroll 1
    for (int ks0 = 0; ks0 < 32; ks0 += 4) {
        PB_STEP(0, bv0)
        PB_STEP(1, bv1)
        PB_STEP(2, bv2)
        PB_STEP(3, bv3)
    }
#undef PB_STEP
    __syncthreads();   // all agg reads done; safe to overwrite with C

    // C layout: col(l15)=f within wave slice, row(lhi*4+i)=node (m89-verified)
    {
        int f = wv * 16 + l15;
#pragma unroll
        for (int i = 0; i < 4; ++i) {
            int n0 = lhi * 4 + i;
            cst[n0 * 132 + f] = acc0[i];
            cst[(n0 + 16) * 132 + f] = acc1[i];
        }
    }
    __syncthreads();

    // relu + coalesced store: thread t -> node t>>4, feats (t&15)*8..+8
    {
        int node = t >> 4;
        int f0 = (t & 15) * 8;
        int gnode = nb0 + node;
        if (gnode < nnodes) {
            const float* cr = cst + node * 132 + f0;
            float4 o0, o1;
            o0.x = fmaxf(cr[0], 0.f); o0.y = fmaxf(cr[1], 0.f);
            o0.z = fmaxf(cr[2], 0.f); o0.w = fmaxf(cr[3], 0.f);
            o1.x = fmaxf(cr[4], 0.f); o1.y = fmaxf(cr[5], 0.f);
            o1.z = fmaxf(cr[6], 0.f); o1.w = fmaxf(cr[7], 0.f);
            float4* op = reinterpret_cast<float4*>(out + (size_t)gnode * FEAT + f0);
            op[0] = o0;
            op[1] = o1;
        }
    }
}

// ---------------------------------------------------------------------------
// ONE cooperative kernel: prep + zero -> grid.sync -> fill -> grid.sync ->
// persistent tile loop. Grid sized to exact co-residency by the launcher.
__global__ __launch_bounds__(512, 4) void k_fused(
    const float* __restrict__ h, const float* __restrict__ gwt,
    const float* __restrict__ w, const float* __restrict__ nrm,
    const int* __restrict__ src, const int* __restrict__ dstv,
    const int* __restrict__ rel,
    float* __restrict__ sg, bf16_t* __restrict__ hb, bf16_t* __restrict__ wt2,
    int* __restrict__ cur, PackedEdge* __restrict__ slab,
    PackedEdge* __restrict__ ovfrec, int* __restrict__ ovfbk,
    int* __restrict__ ovfcnt,
    float* __restrict__ out, int N, int E, int nbk) {
    __shared__ __align__(16) char lds_raw[BN * KTOT * sizeof(bf16_t)];   // 64 KiB
    __shared__ __align__(8) PackedEdge elist[ECAP];
    __shared__ int kcnt[256];
    __shared__ int kbase[257];
    __shared__ int kwork[256];

    const int t = threadIdx.x;
    const int gid = blockIdx.x * 512 + t;
    const int nthreads = gridDim.x * 512;
    const int lane = t & 63;

    // ---- stage A: wt2 convert + cursor zero + per-node prep ----
    for (int i = gid; i < NRELS * FEAT * FEAT; i += nthreads) {
        int r = i >> 14;
        int rem = i & 16383;
        int d = rem >> 7;
        int f = rem & 127;
        wt2[(size_t)f * KTOT + r * FEAT + d] = (bf16_t)w[i];
    }
    for (int i = gid; i < nbk * CPAD + 1; i += nthreads) cur[i] = 0;  // + ovfcnt
    {
        const int gw_id = gid >> 6;
        const int nwaves = nthreads >> 6;
        for (int node = gw_id; node < N; node += nwaves)
            do_prep(node, lane, h, gwt, sg, hb);
    }
    __threadfence();
    cg::this_grid().sync();

    // ---- stage B: edge fill ----
    for (int e = gid; e < E; e += nthreads)
        do_fill(e, src, dstv, rel, nrm, sg, cur, slab, ovfrec, ovfbk, ovfcnt);
    __threadfence();
    cg::this_grid().sync();

    // ---- stage C: persistent tiles ----
    const int novf = *ovfcnt;
    const bf16_t* bp = wt2 + (size_t)((t >> 6) * 16 + (lane & 15)) * KTOT
                     + (lane >> 4) * 8;
    bf16x8_t bv0 = *reinterpret_cast<const bf16x8_t*>(bp);
    bf16x8_t bv1 = *reinterpret_cast<const bf16x8_t*>(bp + 32);
    bf16x8_t bv2 = *reinterpret_cast<const bf16x8_t*>(bp + 64);
    bf16x8_t bv3 = *reinterpret_cast<const bf16x8_t*>(bp + 96);
    for (int tile = blockIdx.x; tile < nbk; tile += gridDim.x) {
        __syncthreads();   // prev epilogue reads vs next agg zero
        tile_body(tile, t, hb, wt2, slab, cur, ovfrec, ovfbk, novf, out, N,
                  lds_raw, elist, kcnt, kbase, kwork, bp, bv0, bv1, bv2, bv3);
    }
}

// ---------------------------------------------------------------------------
// Fallback path (non-cooperative): 3 dispatches, round-8 semantics.
__global__ __launch_bounds__(256) void k_pre_fb(
    const float* __restrict__ h, const float* __restrict__ gwt,
    const float* __restrict__ w, float* __restrict__ sg,
    bf16_t* __restrict__ hb, bf16_t* __restrict__ wt2,
    int* __restrict__ cur, int N, int nbk) {
    const int t = threadIdx.x;
    const int gid = blockIdx.x * 256 + t;
    const int nthreads = gridDim.x * 256;
    for (int i = gid; i < NRELS * FEAT * FEAT; i += nthreads) {
        int r = i >> 14;
        int rem = i & 16383;
        int d = rem >> 7;
        int f = rem & 127;
        wt2[(size_t)f * KTOT + r * FEAT + d] = (bf16_t)w[i];
    }
    for (int i = gid; i < nbk * CPAD + 1; i += nthreads) cur[i] = 0;
    const int gw_id = gid >> 6;
    const int nwaves = nthreads >> 6;
    const int lane = t & 63;
    for (int node = gw_id; node < N; node += nwaves)
        do_prep(node, lane, h, gwt, sg, hb);
}

__global__ void k_fills_fb(const int* __restrict__ src, const int* __restrict__ dstv,
                           const int* __restrict__ rel, const float* __restrict__ nrm,
                           const float* __restrict__ sg, int* __restrict__ cur,
                           PackedEdge* __restrict__ slab,
                           PackedEdge* __restrict__ ovfrec, int* __restrict__ ovfbk,
                           int* __restrict__ ovfcnt, int nedges) {
    int e = blockIdx.x * blockDim.x + threadIdx.x;
    if (e >= nedges) return;
    do_fill(e, src, dstv, rel, nrm, sg, cur, slab, ovfrec, ovfbk, ovfcnt);
}

__global__ __launch_bounds__(512, 4) void k_aggemm_fb(
    const bf16_t* __restrict__ hb, const bf16_t* __restrict__ wt2,
    const PackedEdge* __restrict__ slab, const int* __restrict__ cur,
    const PackedEdge* __restrict__ ovfrec, const int* __restrict__ ovfbk,
    const int* __restrict__ ovfcnt, float* __restrict__ out, int nnodes) {
    __shared__ __align__(16) char lds_raw[BN * KTOT * sizeof(bf16_t)];
    __shared__ __align__(8) PackedEdge elist[ECAP];
    __shared__ int kcnt[256];
    __shared__ int kbase[257];
    __shared__ int kwork[256];
    const int t = threadIdx.x;
    const int lane = t & 63;
    const int novf = *ovfcnt;
    const bf16_t* bp = wt2 + (size_t)((t >> 6) * 16 + (lane & 15)) * KTOT
                     + (lane >> 4) * 8;
    bf16x8_t bv0 = *reinterpret_cast<const bf16x8_t*>(bp);
    bf16x8_t bv1 = *reinterpret_cast<const bf16x8_t*>(bp + 32);
    bf16x8_t bv2 = *reinterpret_cast<const bf16x8_t*>(bp + 64);
    bf16x8_t bv3 = *reinterpret_cast<const bf16x8_t*>(bp + 96);
    tile_body(blockIdx.x, t, hb, wt2, slab, cur, ovfrec, ovfbk, novf, out, nnodes,
              lds_raw, elist, kcnt, kbase, kwork, bp, bv0, bv1, bv2, bv3);
}

// ---------------------------------------------------------------------------
extern "C" void kernel_launch(void* const* d_in, const int* in_sizes, int n_in,
                              void* d_out, int out_size, void* d_ws, size_t ws_size,
                              hipStream_t stream) {
    const float* h = (const float*)d_in[0];
    const float* w = (const float*)d_in[1];
    const float* gwt = (const float*)d_in[2];
    const float* nrm = (const float*)d_in[3];
    const int* src = (const int*)d_in[4];
    const int* dst = (const int*)d_in[5];
    const int* rel = (const int*)d_in[6];
    float* out = (float*)d_out;

    const int N = in_sizes[0] / FEAT;
    const int E = in_sizes[4];
    int nbk = (N + BN - 1) / BN;

    char* ws = (char*)d_ws;
    const size_t wt2B = align256((size_t)FEAT * KTOT * sizeof(bf16_t));   // 256 KiB
    const size_t hbB  = align256((size_t)N * FEAT * sizeof(bf16_t));      // 25.6 MB
    const size_t sgB  = align256((size_t)N * NRELS * sizeof(float));      // 3.2 MB
    const size_t cuB  = align256(((size_t)nbk * CPAD + 1) * sizeof(int));
    const size_t slB  = align256((size_t)nbk * ECAP * sizeof(PackedEdge)); // 6.4 MB
    const size_t ovB  = align256((size_t)E * sizeof(PackedEdge));

    bf16_t* wt2 = (bf16_t*)ws;
    bf16_t* hb = (bf16_t*)(ws + wt2B);
    float* sg = (float*)(ws + wt2B + hbB);
    int* cur = (int*)(ws + wt2B + hbB + sgB);          // [nbk*CPAD] + ovfcnt
    int* ovfcnt = cur + (size_t)nbk * CPAD;
    PackedEdge* slab = (PackedEdge*)(ws + wt2B + hbB + sgB + cuB);
    PackedEdge* ovfrec = (PackedEdge*)(ws + wt2B + hbB + sgB + cuB + slB);
    int* ovfbk = (int*)(ws + wt2B + hbB + sgB + cuB + slB + ovB);

    // one-time cooperative capability probe (host queries only; capture-safe)
    static int coopMode = -1;   // -1 unknown, 0 fallback, 1 cooperative
    static int coopGrid = 0;
    if (coopMode < 0) {
        int dev = 0;
        (void)hipGetDevice(&dev);
        int hasCoop = 0, numCU = 0, bpc = 0;
        (void)hipDeviceGetAttribute(&hasCoop, hipDeviceAttributeCooperativeLaunch, dev);
        (void)hipDeviceGetAttribute(&numCU, hipDeviceAttributeMultiprocessorCount, dev);
        hipError_t oe = hipOccupancyMaxActiveBlocksPerMultiprocessor(
            &bpc, k_fused, 512, 0);
        if (hasCoop && oe == hipSuccess && bpc >= 1 && numCU > 0) {
            coopMode = 1;
            coopGrid = numCU * bpc;
        } else {
            coopMode = 0;
        }
    }

    if (coopMode == 1) {
        void* args[] = {
            (void*)&h, (void*)&gwt, (void*)&w, (void*)&nrm,
            (void*)&src, (void*)&dst, (void*)&rel,
            (void*)&sg, (void*)&hb, (void*)&wt2,
            (void*)&cur, (void*)&slab, (void*)&ovfrec, (void*)&ovfbk,
            (void*)&ovfcnt, (void*)&out, (void*)&N, (void*)&E, (void*)&nbk};
        hipError_t le = hipLaunchCooperativeKernel(
            k_fused, dim3(coopGrid), dim3(512), args, 0, stream);
        if (le == hipSuccess) return;
        (void)hipGetLastError();   // clear; fall through to fallback
        coopMode = 0;
    }

    // ------------------ fallback: 3-dispatch round-8 path ------------------
    k_pre_fb<<<4096, 256, 0, stream>>>(h, gwt, w, sg, hb, wt2, cur, N, nbk);
    k_fills_fb<<<(E + 255) / 256, 256, 0, stream>>>(src, dst, rel, nrm, sg, cur,
                                                    slab, ovfrec, ovfbk, ovfcnt, E);
    k_aggemm_fb<<<nbk, 512, 0, stream>>>(hb, wt2, slab, cur, ovfrec, ovfbk, ovfcnt,
                                         out, N);
}

// Round 10
// 294.032 us; speedup vs baseline: 1.6652x; 1.6652x over previous
//
#include <hip/hip_runtime.h>
#include <hip/hip_bf16.h>

#define FEAT 128
#define NRELS 8
#define KTOT 1024          // NRELS * FEAT
#define BN 32              // dst nodes per aggemm block
#define ECAP 256           // slab capacity per 32-node bucket (avg ~192)
#define CPAD 16            // cursor padding: one int per 64B line

typedef __bf16 bf16_t;
typedef __bf16 bf16x2_t __attribute__((ext_vector_type(2)));
typedef __bf16 bf16x8_t __attribute__((ext_vector_type(8)));
typedef float f32x4 __attribute__((ext_vector_type(4)));

struct __align__(8) PackedEdge { int row; float scale; };
// row = (src<<8) | (local<<3) | rel ; key = row & 255 ; src = row >> 8

static inline size_t align256(size_t x) { return (x + 255) & ~(size_t)255; }

// ---------------------------------------------------------------------------
// Prep: wt2 convert + cursor/ovfcnt zero + per-node {h->hb bf16, 8-rel gate}.
// (Round-9 fallback structure, harness-verified; drops the memset dispatch.)
__global__ __launch_bounds__(256) void k_prep(
    const float* __restrict__ h, const float* __restrict__ gwt,
    const float* __restrict__ w, float* __restrict__ sg,
    bf16_t* __restrict__ hb, bf16_t* __restrict__ wt2,
    int* __restrict__ cur, int N, int nbk) {
    const int t = threadIdx.x;
    const int gid = blockIdx.x * 256 + t;
    const int nthreads = gridDim.x * 256;
    for (int i = gid; i < NRELS * FEAT * FEAT; i += nthreads) {
        int r = i >> 14;
        int rem = i & 16383;
        int d = rem >> 7;
        int f = rem & 127;
        wt2[(size_t)f * KTOT + r * FEAT + d] = (bf16_t)w[i];
    }
    for (int i = gid; i < nbk * CPAD + 1; i += nthreads) cur[i] = 0;  // + ovfcnt

    const int gw_id = gid >> 6;
    const int nwaves = nthreads >> 6;
    const int lane = t & 63;
    for (int node = gw_id; node < N; node += nwaves) {
        float2 hv2 = *reinterpret_cast<const float2*>(h + (size_t)node * FEAT + lane * 2);
        bf16x2_t hc;
        hc.x = (bf16_t)hv2.x;
        hc.y = (bf16_t)hv2.y;
        *reinterpret_cast<bf16x2_t*>(hb + (size_t)node * FEAT + lane * 2) = hc;

        int r = lane >> 3;          // relation 0..7
        int g = lane & 7;           // d-group
        const float4* hp = reinterpret_cast<const float4*>(h + (size_t)node * FEAT + g * 16);
        const float4* wp = reinterpret_cast<const float4*>(gwt + r * FEAT + g * 16);
        float s = 0.f;
#pragma unroll
        for (int i = 0; i < 4; ++i) {
            float4 a = hp[i];
            float4 b = wp[i];
            s += a.x * b.x + a.y * b.y + a.z * b.z + a.w * b.w;
        }
        s += __shfl_xor(s, 1, 64);
        s += __shfl_xor(s, 2, 64);
        s += __shfl_xor(s, 4, 64);
        if (g == 0) sg[(size_t)node * NRELS + r] = 1.0f / (1.0f + __expf(-s));
    }
}

// ---------------------------------------------------------------------------
// Atomic-append fill into fixed-capacity per-bucket slabs (verified r8).
__global__ void k_fills(const int* __restrict__ src, const int* __restrict__ dstv,
                        const int* __restrict__ rel, const float* __restrict__ nrm,
                        const float* __restrict__ sg, int* __restrict__ cur,
                        PackedEdge* __restrict__ slab, PackedEdge* __restrict__ ovfrec,
                        int* __restrict__ ovfbk, int* __restrict__ ovfcnt, int nedges) {
    int e = blockIdx.x * blockDim.x + threadIdx.x;
    if (e >= nedges) return;
    int d = dstv[e];
    int s = src[e];
    int r = rel[e];
    int bk = d >> 5;
    PackedEdge p;
    p.row = (s << 8) | ((d & 31) << 3) | r;
    p.scale = nrm[e] * sg[(size_t)s * NRELS + r];
    int pos = atomicAdd(&cur[bk * CPAD], 1);
    if (pos < ECAP) {
        slab[(size_t)bk * ECAP + pos] = p;
    } else {
        int op = atomicAdd(ovfcnt, 1);
        ovfrec[op] = p;
        ovfbk[op] = bk;
    }
}

// ---------------------------------------------------------------------------
// Fused sort + aggregate + GEMM + relu (round-8 body; phase A re-parallelized).
// Phase A now runs 64 chains/block: each node's 256B row is split between TWO
// 8-lane groups (half-row each, cidx = half*8 + lane&7). Same edge order and
// same per-feature fp32 accumulation -> numerics identical to round 8; the
// latency-bound gather has 2x the independent chains (the measured limiter:
// 137us flat across 4 phase-A variants at 32 chains).
__global__ __launch_bounds__(512, 4) void k_aggemm(const bf16_t* __restrict__ hb,
                                                   const bf16_t* __restrict__ wt2,
                                                   const PackedEdge* __restrict__ slab,
                                                   const int* __restrict__ cur,
                                                   const PackedEdge* __restrict__ ovfrec,
                                                   const int* __restrict__ ovfbk,
                                                   const int* __restrict__ ovfcnt,
                                                   float* __restrict__ out, int nnodes) {
    __shared__ __align__(16) char lds_raw[BN * KTOT * sizeof(bf16_t)];   // 64 KiB
    __shared__ __align__(8) PackedEdge elist[ECAP];
    __shared__ int kcnt[256];
    __shared__ int kbase[257];
    __shared__ int kwork[256];
    float* cst = (float*)lds_raw;                 // aliased C-stage [32][132]
    const int t = threadIdx.x;
    const int nb0 = blockIdx.x * BN;
    const int lane = t & 63;
    const int wv = t >> 6;               // 0..7
    const int l15 = lane & 15;
    const int lhi = lane >> 4;

    // Phase-B bv preload (completes during sort/phase A)
    const bf16_t* bp = wt2 + (size_t)(wv * 16 + l15) * KTOT + lhi * 8;
    bf16x8_t bv0 = *reinterpret_cast<const bf16x8_t*>(bp);
    bf16x8_t bv1 = *reinterpret_cast<const bf16x8_t*>(bp + 32);
    bf16x8_t bv2 = *reinterpret_cast<const bf16x8_t*>(bp + 64);
    bf16x8_t bv3 = *reinterpret_cast<const bf16x8_t*>(bp + 96);

    // zero agg tile
    {
        f32x4 z = {0.f, 0.f, 0.f, 0.f};
#pragma unroll
        for (int i = 0; i < 8; ++i)
            reinterpret_cast<f32x4*>(lds_raw)[t + i * 512] = z;
    }

    const int cnt = cur[blockIdx.x * CPAD];
    const int nE = cnt < ECAP ? cnt : ECAP;
    if (t < 256) kcnt[t] = 0;
    __syncthreads();

    // coalesced slab load + count
    PackedEdge myrec = {0, 0.f};
    if (t < nE) {
        myrec = slab[(size_t)blockIdx.x * ECAP + t];
        atomicAdd(&kcnt[myrec.row & 255], 1);
    }
    __syncthreads();

    // 64-lane shfl scan over 256 counters (wave 0)
    if (t < 64) {
        int c0 = kcnt[t * 4], c1 = kcnt[t * 4 + 1];
        int c2 = kcnt[t * 4 + 2], c3 = kcnt[t * 4 + 3];
        int tot = c0 + c1 + c2 + c3;
        int incl = tot;
#pragma unroll
        for (int off = 1; off < 64; off <<= 1) {
            int y = __shfl_up(incl, off, 64);
            if (t >= off) incl += y;
        }
        int excl = incl - tot;
        kbase[t * 4] = excl;               kwork[t * 4] = excl;
        kbase[t * 4 + 1] = excl + c0;      kwork[t * 4 + 1] = excl + c0;
        kbase[t * 4 + 2] = excl + c0 + c1; kwork[t * 4 + 2] = excl + c0 + c1;
        kbase[t * 4 + 3] = excl + c0 + c1 + c2;
        kwork[t * 4 + 3] = excl + c0 + c1 + c2;
        if (t == 63) kbase[256] = excl + tot;   // = nE
    }
    __syncthreads();

    // scatter into sorted elist
    if (t < nE) elist[atomicAdd(&kwork[myrec.row & 255], 1)] = myrec;
    __syncthreads();

    // ---------------- Phase A: 64-chain aggregation (8 lanes/chain) ----------------
    {
        const int g2 = t >> 3;                       // chain 0..63
        const int node = g2 >> 1;                    // local node 0..31
        const int cidx = ((g2 & 1) << 3) | (t & 7);  // 16B chunk 0..15 in row
        const int sw = node & 15;
        const int jbeg = kbase[node * 8];
        const int jend = kbase[node * 8 + 8];
        if (jbeg < jend) {
            float a[8];
#pragma unroll
            for (int i = 0; i < 8; ++i) a[i] = 0.f;
            int cur_r;

            auto ldrec = [&](int idx) {
                return elist[idx < jend ? idx : jend - 1];   // LDS broadcast
            };
            auto ldrow = [&](const PackedEdge& p) {
                return *reinterpret_cast<const bf16x8_t*>(
                    hb + ((size_t)(p.row >> 8) << 7) + cidx * 8);
            };
            auto flush = [&](int rr) {       // RMW add (zeros on first touch)
                int chunk = (rr * 16 + cidx) ^ sw;
                bf16_t* dp = reinterpret_cast<bf16_t*>(
                    lds_raw + (size_t)node * 2048 + chunk * 16);
                bf16x8_t old = *reinterpret_cast<const bf16x8_t*>(dp);
                bf16x8_t o;
#pragma unroll
                for (int i = 0; i < 8; ++i) o[i] = (bf16_t)((float)old[i] + a[i]);
                *reinterpret_cast<bf16x8_t*>(dp) = o;
            };
            auto consume = [&](const PackedEdge& p, const bf16x8_t& v, int idx) {
                if (idx < jend) {
                    int r = p.row & 7;
                    if (r != cur_r) {        // chain-uniform branch
                        flush(cur_r);
#pragma unroll
                        for (int i = 0; i < 8; ++i) a[i] = 0.f;
                        cur_r = r;
                    }
                    float s = p.scale;
#pragma unroll
                    for (int i = 0; i < 8; ++i) a[i] += (float)v[i] * s;
                }
            };

            PackedEdge p0 = ldrec(jbeg), p1 = ldrec(jbeg + 1);
            PackedEdge p2 = ldrec(jbeg + 2), p3 = ldrec(jbeg + 3);
            PackedEdge q0 = ldrec(jbeg + 4), q1 = ldrec(jbeg + 5);
            PackedEdge q2 = ldrec(jbeg + 6), q3 = ldrec(jbeg + 7);
            bf16x8_t v0 = ldrow(p0);
            bf16x8_t v1 = ldrow(p1);
            bf16x8_t v2 = ldrow(p2);
            bf16x8_t v3 = ldrow(p3);
            cur_r = p0.row & 7;

#pragma unroll 1
            for (int j = jbeg; j < jend; j += 4) {
                PackedEdge r0 = ldrec(j + 8), r1 = ldrec(j + 9);
                PackedEdge r2 = ldrec(j + 10), r3 = ldrec(j + 11);
                consume(p0, v0, j);
                consume(p1, v1, j + 1);
                consume(p2, v2, j + 2);
                consume(p3, v3, j + 3);
                v0 = ldrow(q0); v1 = ldrow(q1); v2 = ldrow(q2); v3 = ldrow(q3);
                p0 = q0; p1 = q1; p2 = q2; p3 = q3;
                q0 = r0; q1 = r1; q2 = r2; q3 = r3;
            }
            flush(cur_r);
        }

        // -------- rare overflow drain (normally novf == 0) --------
        int novf = *ovfcnt;
        if (novf > 0) {
#pragma unroll 1
            for (int i = 0; i < novf; ++i) {
                if (ovfbk[i] != blockIdx.x) continue;
                PackedEdge p = ovfrec[i];
                if (((p.row >> 3) & 31) != node) continue;
                bf16x8_t v = *reinterpret_cast<const bf16x8_t*>(
                    hb + ((size_t)(p.row >> 8) << 7) + cidx * 8);
                int chunk = ((p.row & 7) * 16 + cidx) ^ sw;
                bf16_t* dp = reinterpret_cast<bf16_t*>(
                    lds_raw + (size_t)node * 2048 + chunk * 16);
                bf16x8_t old = *reinterpret_cast<const bf16x8_t*>(dp);
                bf16x8_t o;
#pragma unroll
                for (int k = 0; k < 8; ++k)
                    o[k] = (bf16_t)((float)old[k] + (float)v[k] * p.scale);
                *reinterpret_cast<bf16x8_t*>(dp) = o;
            }
        }
    }
    __syncthreads();

    // ---------------- Phase B: GEMM with 4-deep bv prefetch ----------------
    f32x4 acc0 = {0.f, 0.f, 0.f, 0.f};
    f32x4 acc1 = {0.f, 0.f, 0.f, 0.f};
    const char* a0p = lds_raw + (size_t)l15 * 2048;        // node rows 0..15
    const char* a1p = a0p + 16 * 2048;                     // node rows 16..31
    const int swb = l15;                 // (16+l15)&15 == l15 : matches write

#define PB_STEP(I, BV)                                                         \
    {                                                                          \
        int ks = ks0 + (I);                                                    \
        int coff = ((ks * 4 + lhi) ^ swb) << 4;                                \
        bf16x8_t av0 = *reinterpret_cast<const bf16x8_t*>(a0p + coff);         \
        bf16x8_t av1 = *reinterpret_cast<const bf16x8_t*>(a1p + coff);         \
        bf16x8_t nxt = *reinterpret_cast<const bf16x8_t*>(                     \
            bp + (((ks + 4) & 31) * 32));                                      \
        acc0 = __builtin_amdgcn_mfma_f32_16x16x32_bf16(av0, BV, acc0, 0, 0, 0);\
        acc1 = __builtin_amdgcn_mfma_f32_16x16x32_bf16(av1, BV, acc1, 0, 0, 0);\
        BV = nxt;                                                              \
    }

#pragma unroll 1
    for (int ks0 = 0; ks0 < 32; ks0 += 4) {
        PB_STEP(0, bv0)
        PB_STEP(1, bv1)
        PB_STEP(2, bv2)
        PB_STEP(3, bv3)
    }
#undef PB_STEP
    __syncthreads();   // all agg reads done; safe to overwrite with C

    // C layout: col(l15)=f within wave slice, row(lhi*4+i)=node (m89-verified)
    {
        int f = wv * 16 + l15;
#pragma unroll
        for (int i = 0; i < 4; ++i) {
            int n0 = lhi * 4 + i;
            cst[n0 * 132 + f] = acc0[i];
            cst[(n0 + 16) * 132 + f] = acc1[i];
        }
    }
    __syncthreads();

    // relu + coalesced store: thread t -> node t>>4, feats (t&15)*8..+8
    {
        int node = t >> 4;
        int f0 = (t & 15) * 8;
        int gnode = nb0 + node;
        if (gnode < nnodes) {
            const float* cr = cst + node * 132 + f0;
            float4 o0, o1;
            o0.x = fmaxf(cr[0], 0.f); o0.y = fmaxf(cr[1], 0.f);
            o0.z = fmaxf(cr[2], 0.f); o0.w = fmaxf(cr[3], 0.f);
            o1.x = fmaxf(cr[4], 0.f); o1.y = fmaxf(cr[5], 0.f);
            o1.z = fmaxf(cr[6], 0.f); o1.w = fmaxf(cr[7], 0.f);
            float4* op = reinterpret_cast<float4*>(out + (size_t)gnode * FEAT + f0);
            op[0] = o0;
            op[1] = o1;
        }
    }
}

// ---------------------------------------------------------------------------
extern "C" void kernel_launch(void* const* d_in, const int* in_sizes, int n_in,
                              void* d_out, int out_size, void* d_ws, size_t ws_size,
                              hipStream_t stream) {
    const float* h = (const float*)d_in[0];
    const float* w = (const float*)d_in[1];
    const float* gwt = (const float*)d_in[2];
    const float* nrm = (const float*)d_in[3];
    const int* src = (const int*)d_in[4];
    const int* dst = (const int*)d_in[5];
    const int* rel = (const int*)d_in[6];
    float* out = (float*)d_out;

    const int N = in_sizes[0] / FEAT;
    const int E = in_sizes[4];
    const int nbk = (N + BN - 1) / BN;

    char* ws = (char*)d_ws;
    const size_t wt2B = align256((size_t)FEAT * KTOT * sizeof(bf16_t));   // 256 KiB
    const size_t hbB  = align256((size_t)N * FEAT * sizeof(bf16_t));      // 25.6 MB
    const size_t sgB  = align256((size_t)N * NRELS * sizeof(float));      // 3.2 MB
    const size_t cuB  = align256(((size_t)nbk * CPAD + 1) * sizeof(int));
    const size_t slB  = align256((size_t)nbk * ECAP * sizeof(PackedEdge)); // 6.4 MB
    const size_t ovB  = align256((size_t)E * sizeof(PackedEdge));

    bf16_t* wt2 = (bf16_t*)ws;
    bf16_t* hb = (bf16_t*)(ws + wt2B);
    float* sg = (float*)(ws + wt2B + hbB);
    int* cur = (int*)(ws + wt2B + hbB + sgB);          // [nbk*CPAD] + ovfcnt
    int* ovfcnt = cur + (size_t)nbk * CPAD;
    PackedEdge* slab = (PackedEdge*)(ws + wt2B + hbB + sgB + cuB);
    PackedEdge* ovfrec = (PackedEdge*)(ws + wt2B + hbB + sgB + cuB + slB);
    int* ovfbk = (int*)(ws + wt2B + hbB + sgB + cuB + slB + ovB);

    k_prep<<<4096, 256, 0, stream>>>(h, gwt, w, sg, hb, wt2, cur, N, nbk);
    k_fills<<<(E + 255) / 256, 256, 0, stream>>>(src, dst, rel, nrm, sg, cur, slab,
                                                 ovfrec, ovfbk, ovfcnt, E);
    k_aggemm<<<nbk, 512, 0, stream>>>(hb, wt2, slab, cur, ovfrec, ovfbk, ovfcnt,
                                      out, N);
}